// Round 4
// baseline (53.065 us; speedup 1.0000x reference)
//
#include <hip/hip_runtime.h>
#include <math.h>

#define B_SZ 16
#define K_PTS 4096
#define ALPHA 1.1f

#define JS 16                 // j-tiles per row
#define JTT (K_PTS / JS)      // 256 points per j-tile
#define ICH 1024              // i-points covered per block
#define IPT 4                 // i-points per thread (ILP)
#define THR 256

#define BIGF 3.0e38f

__device__ __forceinline__ void insert2(float d, float& m0, float& m1) {
    m1 = __builtin_amdgcn_fmed3f(d, m0, m1);
    m0 = fminf(d, m0);
}
__device__ __forceinline__ void insert3(float d, float& m0, float& m1, float& m2) {
    m2 = __builtin_amdgcn_fmed3f(d, m1, m2);
    m1 = __builtin_amdgcn_fmed3f(d, m0, m1);
    m0 = fminf(d, m0);
}

// One dispatch: grid (64, B). bx = ic*16 + js. Off-diagonal blocks (j-tile
// cannot contain i==j) keep top-2 of d' = -2<xi,xj> + ||xj||^2 (5 VALU/pair).
// Diagonal blocks keep top-3 and drop m0 (== self, the strict tile min) for
// the single IPT slot k* whose i lies in this j-tile. ws: 2 slots/pt/tile.
__global__ __launch_bounds__(256) void sor_partial2(
    const float* __restrict__ x, float* __restrict__ ws)
{
    __shared__ float4 pts[JTT];   // 4 KiB: (x, y, z, ||x||^2)
    const int b  = blockIdx.y;
    const int ic = blockIdx.x >> 4;
    const int js = blockIdx.x & 15;
    const int j0 = js * JTT;
    const float* xb = x + (size_t)b * K_PTS * 3;

    for (int p = threadIdx.x; p < JTT; p += THR) {
        float a0 = xb[(j0 + p) * 3 + 0];
        float a1 = xb[(j0 + p) * 3 + 1];
        float a2 = xb[(j0 + p) * 3 + 2];
        pts[p] = make_float4(a0, a1, a2, a0 * a0 + a1 * a1 + a2 * a2);
    }
    __syncthreads();

    const int ibase = ic * ICH + threadIdx.x;
    float x2[IPT], y2[IPT], z2[IPT], m0[IPT], m1[IPT];
    #pragma unroll
    for (int k = 0; k < IPT; ++k) {
        const int i = ibase + k * THR;
        x2[k] = -2.0f * xb[i * 3 + 0];
        y2[k] = -2.0f * xb[i * 3 + 1];
        z2[k] = -2.0f * xb[i * 3 + 2];
        m0[k] = BIGF; m1[k] = BIGF;
    }

    float* wbase = ws + (size_t)((b * JS + js) * 2) * K_PTS;

    if ((js >> 2) == ic) {
        // ---- diagonal tile: top-3, drop self at write-out ----
        float m2[IPT];
        #pragma unroll
        for (int k = 0; k < IPT; ++k) m2[k] = BIGF;

        #pragma unroll 4
        for (int j = 0; j < JTT; ++j) {
            const float4 pj = pts[j];
            #pragma unroll
            for (int k = 0; k < IPT; ++k) {
                float t = fmaf(z2[k], pj.z, pj.w);
                t = fmaf(y2[k], pj.y, t);
                float d = fmaf(x2[k], pj.x, t);
                insert3(d, m0[k], m1[k], m2[k]);
            }
        }
        const int kstar = js & 3;   // i = ic*1024 + k*256 + tid is in tile iff k == js&3
        #pragma unroll
        for (int k = 0; k < IPT; ++k) {
            const int i = ibase + k * THR;
            const bool drop0 = (k == kstar);
            wbase[i]         = drop0 ? m1[k] : m0[k];
            wbase[K_PTS + i] = drop0 ? m2[k] : m1[k];
        }
    } else {
        // ---- off-diagonal tile: top-2 ----
        #pragma unroll 4
        for (int j = 0; j < JTT; ++j) {
            const float4 pj = pts[j];
            #pragma unroll
            for (int k = 0; k < IPT; ++k) {
                float t = fmaf(z2[k], pj.z, pj.w);
                t = fmaf(y2[k], pj.y, t);
                float d = fmaf(x2[k], pj.x, t);
                insert2(d, m0[k], m1[k]);
            }
        }
        #pragma unroll
        for (int k = 0; k < IPT; ++k) {
            const int i = ibase + k * THR;
            wbase[i]         = m0[k];
            wbase[K_PTS + i] = m1[k];
        }
    }
}

// Fused merge + threshold + output. One block (1024 thr) per batch; each
// thread merges 4 points' 32 partial values in registers, then two-pass
// mean/std(ddof=1), then mask + zeroed points.
__global__ __launch_bounds__(1024) void sor_merge_mask(
    const float* __restrict__ x, const float* __restrict__ ws,
    float* __restrict__ out)
{
    const int b = blockIdx.x;
    const int tid = threadIdx.x;
    float* maskout = out + (size_t)B_SZ * K_PTS * 3;
    float* selpc = out;

    __shared__ float red[16];
    __shared__ float sh_mean, sh_thr;

    float v[4];
    #pragma unroll
    for (int k = 0; k < 4; ++k) {
        const int i = tid + k * 1024;
        float m0 = BIGF, m1 = BIGF;
        #pragma unroll
        for (int js = 0; js < JS; ++js) {
            const float* w = ws + (size_t)((b * JS + js) * 2) * K_PTS + i;
            float d0 = w[0];
            float d1 = w[K_PTS];
            insert2(d0, m0, m1);
            insert2(d1, m0, m1);
        }
        const size_t base = ((size_t)b * K_PTS + i) * 3;
        const float a0 = x[base + 0];
        const float a1 = x[base + 1];
        const float a2 = x[base + 2];
        const float xx = a0 * a0 + a1 * a1 + a2 * a2;
        // un-shift: true distances are m' + ||xi||^2; (m0,m1) = 2NN sorted.
        v[k] = ((m0 + xx) + (m1 + xx)) * 0.5f;
    }

    float s = 0.0f;
    #pragma unroll
    for (int k = 0; k < 4; ++k) s += v[k];
    #pragma unroll
    for (int off = 32; off > 0; off >>= 1) s += __shfl_down(s, off, 64);
    if ((tid & 63) == 0) red[tid >> 6] = s;
    __syncthreads();
    if (tid == 0) {
        float t = 0.0f;
        for (int w = 0; w < 16; ++w) t += red[w];
        sh_mean = t * (1.0f / (float)K_PTS);
    }
    __syncthreads();
    const float mean = sh_mean;

    float q = 0.0f;
    #pragma unroll
    for (int k = 0; k < 4; ++k) { float dv = v[k] - mean; q += dv * dv; }
    #pragma unroll
    for (int off = 32; off > 0; off >>= 1) q += __shfl_down(q, off, 64);
    if ((tid & 63) == 0) red[tid >> 6] = q;
    __syncthreads();
    if (tid == 0) {
        float t = 0.0f;
        for (int w = 0; w < 16; ++w) t += red[w];
        sh_thr = mean + ALPHA * sqrtf(t / (float)(K_PTS - 1));
    }
    __syncthreads();
    const float thr = sh_thr;

    #pragma unroll
    for (int k = 0; k < 4; ++k) {
        const int i = tid + k * 1024;
        const bool keep = v[k] <= thr;
        maskout[b * K_PTS + i] = keep ? 1.0f : 0.0f;
        const size_t base = ((size_t)b * K_PTS + i) * 3;
        float x0 = x[base + 0];
        float x1 = x[base + 1];
        float x2 = x[base + 2];
        selpc[base + 0] = keep ? x0 : 0.0f;
        selpc[base + 1] = keep ? x1 : 0.0f;
        selpc[base + 2] = keep ? x2 : 0.0f;
    }
}

// ---- Fallback (round-1 structure) used only if d_ws is too small ----
__device__ __forceinline__ void insert3f(float d, float& m0, float& m1, float& m2) {
    m2 = __builtin_amdgcn_fmed3f(d, m1, m2);
    m1 = __builtin_amdgcn_fmed3f(d, m0, m1);
    m0 = fminf(d, m0);
}

__global__ __launch_bounds__(256) void sor_value_kernel(
    const float* __restrict__ x, float* __restrict__ value)
{
    __shared__ float4 pts[K_PTS];
    const int b = blockIdx.y;
    const float* xb = x + (size_t)b * K_PTS * 3;
    for (int p = threadIdx.x; p < K_PTS; p += 256) {
        float a0 = xb[p * 3 + 0];
        float a1 = xb[p * 3 + 1];
        float a2 = xb[p * 3 + 2];
        pts[p] = make_float4(a0, a1, a2, a0 * a0 + a1 * a1 + a2 * a2);
    }
    __syncthreads();
    const int i = blockIdx.x * 256 + threadIdx.x;
    const float4 pi = pts[i];
    float m0 = BIGF, m1 = BIGF, m2 = BIGF;
    #pragma unroll 8
    for (int j = 0; j < K_PTS; ++j) {
        float4 pj = pts[j];
        float dot = pi.x * pj.x + pi.y * pj.y + pi.z * pj.z;
        float d = (pi.w - 2.0f * dot) + pj.w;
        insert3f(d, m0, m1, m2);
    }
    value[b * K_PTS + i] = 0.5f * (m1 + m2);
}

__global__ __launch_bounds__(1024) void sor_mask_kernel(
    const float* __restrict__ x, float* __restrict__ out)
{
    const int b = blockIdx.x;
    const int tid = threadIdx.x;
    float* value = out + (size_t)B_SZ * K_PTS * 3;
    float* selpc = out;
    __shared__ float red[16];
    __shared__ float sh_mean, sh_thr;
    float v[4];
    float s = 0.0f;
    #pragma unroll
    for (int k = 0; k < 4; ++k) { v[k] = value[b * K_PTS + tid + k * 1024]; s += v[k]; }
    #pragma unroll
    for (int off = 32; off > 0; off >>= 1) s += __shfl_down(s, off, 64);
    if ((tid & 63) == 0) red[tid >> 6] = s;
    __syncthreads();
    if (tid == 0) { float t = 0.0f; for (int w = 0; w < 16; ++w) t += red[w]; sh_mean = t / (float)K_PTS; }
    __syncthreads();
    const float mean = sh_mean;
    float q = 0.0f;
    #pragma unroll
    for (int k = 0; k < 4; ++k) { float dv = v[k] - mean; q += dv * dv; }
    #pragma unroll
    for (int off = 32; off > 0; off >>= 1) q += __shfl_down(q, off, 64);
    if ((tid & 63) == 0) red[tid >> 6] = q;
    __syncthreads();
    if (tid == 0) { float t = 0.0f; for (int w = 0; w < 16; ++w) t += red[w]; sh_thr = mean + ALPHA * sqrtf(t / (float)(K_PTS - 1)); }
    __syncthreads();
    const float thr = sh_thr;
    #pragma unroll
    for (int k = 0; k < 4; ++k) {
        const int i = tid + k * 1024;
        const bool keep = v[k] <= thr;
        value[b * K_PTS + i] = keep ? 1.0f : 0.0f;
        const size_t base = ((size_t)b * K_PTS + i) * 3;
        float x0 = x[base + 0]; float x1 = x[base + 1]; float x2 = x[base + 2];
        selpc[base + 0] = keep ? x0 : 0.0f;
        selpc[base + 1] = keep ? x1 : 0.0f;
        selpc[base + 2] = keep ? x2 : 0.0f;
    }
}

extern "C" void kernel_launch(void* const* d_in, const int* in_sizes, int n_in,
                              void* d_out, int out_size, void* d_ws, size_t ws_size,
                              hipStream_t stream)
{
    const float* x = (const float*)d_in[0];
    float* out = (float*)d_out;

    const size_t ws_needed = (size_t)B_SZ * JS * 2 * K_PTS * sizeof(float); // 8.4 MiB

    if (ws_size >= ws_needed) {
        float* ws = (float*)d_ws;
        dim3 gA((K_PTS / ICH) * JS, B_SZ);   // (64, 16) = 1024 blocks
        sor_partial2<<<gA, THR, 0, stream>>>(x, ws);
        sor_merge_mask<<<B_SZ, 1024, 0, stream>>>(x, ws, out);
    } else {
        float* value = out + (size_t)B_SZ * K_PTS * 3;
        dim3 g1(K_PTS / 256, B_SZ);
        sor_value_kernel<<<g1, 256, 0, stream>>>(x, value);
        sor_mask_kernel<<<B_SZ, 1024, 0, stream>>>(x, out);
    }
}

// Round 5
// 45.310 us; speedup vs baseline: 1.1712x; 1.1712x over previous
//
#include <hip/hip_runtime.h>
#include <math.h>

#define B_SZ 16
#define K_PTS 4096
#define ALPHA 1.1f

#define JS 16                 // j-tiles per row
#define JTT (K_PTS / JS)      // 256 points per j-tile
#define ICH 1024              // i-points covered per block
#define THR 256

#define BIGF 3.0e38f

__device__ __forceinline__ void insert2(float d, float& m0, float& m1) {
    m1 = __builtin_amdgcn_fmed3f(d, m0, m1);
    m0 = fminf(d, m0);
}
__device__ __forceinline__ void insert3(float d, float& m0, float& m1, float& m2) {
    m2 = __builtin_amdgcn_fmed3f(d, m1, m2);
    m1 = __builtin_amdgcn_fmed3f(d, m0, m1);
    m0 = fminf(d, m0);
}

// Partial top-2 of shifted distance d' = -2<xi,xj> + ||xj||^2 over one j-tile.
// grid (64, B): bx = ic*16 + js. In diagonal blocks ((js>>2)==ic) the chain
// that owns the self-containing i-range is SWAPPED to chain 0, which keeps
// top-3 and drops m0 (= self, the strict tile min since d'_self = -||xi||^2
// is the unique row minimum). All other chains keep top-2 (5 VALU/pair).
// Load imbalance diag vs off-diag: 21 vs 20 VALU per j (~5%).
__global__ __launch_bounds__(256) void sor_partial2(
    const float* __restrict__ x, float* __restrict__ ws)
{
    __shared__ float4 pts[JTT];   // 4 KiB: (x, y, z, ||x||^2)
    const int b  = blockIdx.y;
    const int ic = blockIdx.x >> 4;
    const int js = blockIdx.x & 15;
    const int j0 = js * JTT;
    const float* xb = x + (size_t)b * K_PTS * 3;

    for (int p = threadIdx.x; p < JTT; p += THR) {
        float a0 = xb[(j0 + p) * 3 + 0];
        float a1 = xb[(j0 + p) * 3 + 1];
        float a2 = xb[(j0 + p) * 3 + 2];
        pts[p] = make_float4(a0, a1, a2, a0 * a0 + a1 * a1 + a2 * a2);
    }
    __syncthreads();

    const int ibase = ic * ICH + threadIdx.x;
    const bool diag = ((js >> 2) == ic);
    const int kstar = js & 3;

    // chain c -> point index idx[c]; in diag blocks swap chain 0 <-> kstar.
    int idx[4];
    #pragma unroll
    for (int c = 0; c < 4; ++c) idx[c] = ibase + c * THR;
    if (diag) { idx[0] = ibase + kstar * THR; idx[kstar] = ibase; }

    float x2[4], y2[4], z2[4], m0[4], m1[4];
    #pragma unroll
    for (int c = 0; c < 4; ++c) {
        const float* p = xb + (size_t)idx[c] * 3;
        x2[c] = -2.0f * p[0];
        y2[c] = -2.0f * p[1];
        z2[c] = -2.0f * p[2];
        m0[c] = BIGF; m1[c] = BIGF;
    }

    float* wbase = ws + (size_t)((b * JS + js) * 2) * K_PTS;

    if (diag) {
        float m2_0 = BIGF;
        #pragma unroll 8
        for (int j = 0; j < JTT; ++j) {
            const float4 pj = pts[j];
            {   // chain 0: contains self -> top-3
                float t = fmaf(z2[0], pj.z, pj.w);
                t = fmaf(y2[0], pj.y, t);
                float d = fmaf(x2[0], pj.x, t);
                insert3(d, m0[0], m1[0], m2_0);
            }
            #pragma unroll
            for (int c = 1; c < 4; ++c) {
                float t = fmaf(z2[c], pj.z, pj.w);
                t = fmaf(y2[c], pj.y, t);
                float d = fmaf(x2[c], pj.x, t);
                insert2(d, m0[c], m1[c]);
            }
        }
        // chain 0 drops m0 (self)
        wbase[idx[0]]         = m1[0];
        wbase[K_PTS + idx[0]] = m2_0;
        #pragma unroll
        for (int c = 1; c < 4; ++c) {
            wbase[idx[c]]         = m0[c];
            wbase[K_PTS + idx[c]] = m1[c];
        }
    } else {
        #pragma unroll 8
        for (int j = 0; j < JTT; ++j) {
            const float4 pj = pts[j];
            #pragma unroll
            for (int c = 0; c < 4; ++c) {
                float t = fmaf(z2[c], pj.z, pj.w);
                t = fmaf(y2[c], pj.y, t);
                float d = fmaf(x2[c], pj.x, t);
                insert2(d, m0[c], m1[c]);
            }
        }
        #pragma unroll
        for (int c = 0; c < 4; ++c) {
            wbase[idx[c]]         = m0[c];
            wbase[K_PTS + idx[c]] = m1[c];
        }
    }
}

// Merge 16 tiles x 2 candidates per point -> mean 2NN distance. 256 blocks.
__global__ __launch_bounds__(256) void sor_merge(
    const float* __restrict__ x, const float* __restrict__ ws,
    float* __restrict__ value)
{
    const int gid = blockIdx.x * 256 + threadIdx.x;   // 0 .. B*K-1
    const int b = gid >> 12;
    const int i = gid & (K_PTS - 1);

    float m0 = BIGF, m1 = BIGF;
    #pragma unroll
    for (int js = 0; js < JS; ++js) {
        const float* w = ws + (size_t)((b * JS + js) * 2) * K_PTS + i;
        insert2(w[0], m0, m1);
        insert2(w[K_PTS], m0, m1);
    }
    const float a0 = x[(size_t)gid * 3 + 0];
    const float a1 = x[(size_t)gid * 3 + 1];
    const float a2 = x[(size_t)gid * 3 + 2];
    const float xx = a0 * a0 + a1 * a1 + a2 * a2;
    // un-shift: true distances are m' + ||xi||^2; (m0,m1) = 2NN sorted.
    value[gid] = ((m0 + xx) + (m1 + xx)) * 0.5f;
}

// One block per batch: mean/std(ddof=1) -> threshold -> mask + zeroed points.
// Reads value from out's mask region, overwrites it with the 0/1 mask.
__global__ __launch_bounds__(1024) void sor_mask_kernel(
    const float* __restrict__ x, float* __restrict__ out)
{
    const int b = blockIdx.x;
    const int tid = threadIdx.x;
    float* value = out + (size_t)B_SZ * K_PTS * 3;
    float* selpc = out;

    __shared__ float red[16];
    __shared__ float sh_mean, sh_thr;

    float v[4];
    float s = 0.0f;
    #pragma unroll
    for (int k = 0; k < 4; ++k) {
        v[k] = value[b * K_PTS + tid + k * 1024];
        s += v[k];
    }
    #pragma unroll
    for (int off = 32; off > 0; off >>= 1) s += __shfl_down(s, off, 64);
    if ((tid & 63) == 0) red[tid >> 6] = s;
    __syncthreads();
    if (tid == 0) {
        float t = 0.0f;
        for (int w = 0; w < 16; ++w) t += red[w];
        sh_mean = t * (1.0f / (float)K_PTS);
    }
    __syncthreads();
    const float mean = sh_mean;

    float q = 0.0f;
    #pragma unroll
    for (int k = 0; k < 4; ++k) { float dv = v[k] - mean; q += dv * dv; }
    #pragma unroll
    for (int off = 32; off > 0; off >>= 1) q += __shfl_down(q, off, 64);
    if ((tid & 63) == 0) red[tid >> 6] = q;
    __syncthreads();
    if (tid == 0) {
        float t = 0.0f;
        for (int w = 0; w < 16; ++w) t += red[w];
        sh_thr = mean + ALPHA * sqrtf(t / (float)(K_PTS - 1));
    }
    __syncthreads();
    const float thr = sh_thr;

    #pragma unroll
    for (int k = 0; k < 4; ++k) {
        const int i = tid + k * 1024;
        const bool keep = v[k] <= thr;
        value[b * K_PTS + i] = keep ? 1.0f : 0.0f;
        const size_t base = ((size_t)b * K_PTS + i) * 3;
        float x0 = x[base + 0];
        float x1 = x[base + 1];
        float x2 = x[base + 2];
        selpc[base + 0] = keep ? x0 : 0.0f;
        selpc[base + 1] = keep ? x1 : 0.0f;
        selpc[base + 2] = keep ? x2 : 0.0f;
    }
}

// ---- Fallback (round-1 structure) used only if d_ws is too small ----
__global__ __launch_bounds__(256) void sor_value_kernel(
    const float* __restrict__ x, float* __restrict__ value)
{
    __shared__ float4 pts[K_PTS];
    const int b = blockIdx.y;
    const float* xb = x + (size_t)b * K_PTS * 3;
    for (int p = threadIdx.x; p < K_PTS; p += 256) {
        float a0 = xb[p * 3 + 0];
        float a1 = xb[p * 3 + 1];
        float a2 = xb[p * 3 + 2];
        pts[p] = make_float4(a0, a1, a2, a0 * a0 + a1 * a1 + a2 * a2);
    }
    __syncthreads();
    const int i = blockIdx.x * 256 + threadIdx.x;
    const float4 pi = pts[i];
    float m0 = BIGF, m1 = BIGF, m2 = BIGF;
    #pragma unroll 8
    for (int j = 0; j < K_PTS; ++j) {
        float4 pj = pts[j];
        float dot = pi.x * pj.x + pi.y * pj.y + pi.z * pj.z;
        float d = (pi.w - 2.0f * dot) + pj.w;
        insert3(d, m0, m1, m2);
    }
    value[b * K_PTS + i] = 0.5f * (m1 + m2);
}

extern "C" void kernel_launch(void* const* d_in, const int* in_sizes, int n_in,
                              void* d_out, int out_size, void* d_ws, size_t ws_size,
                              hipStream_t stream)
{
    const float* x = (const float*)d_in[0];
    float* out = (float*)d_out;
    float* value = out + (size_t)B_SZ * K_PTS * 3;

    const size_t ws_needed = (size_t)B_SZ * JS * 2 * K_PTS * sizeof(float); // 8.4 MiB

    if (ws_size >= ws_needed) {
        float* ws = (float*)d_ws;
        dim3 gA((K_PTS / ICH) * JS, B_SZ);   // (64, 16) = 1024 blocks
        sor_partial2<<<gA, THR, 0, stream>>>(x, ws);
        sor_merge<<<(B_SZ * K_PTS) / 256, 256, 0, stream>>>(x, ws, value);
    } else {
        dim3 g1(K_PTS / 256, B_SZ);
        sor_value_kernel<<<g1, 256, 0, stream>>>(x, value);
    }
    sor_mask_kernel<<<B_SZ, 1024, 0, stream>>>(x, out);
}